// Round 5
// baseline (136.742 us; speedup 1.0000x reference)
//
#include <hip/hip_runtime.h>

// ChamferLoss: x,y [4, 8192, 3] fp32 -> scalar fp32.
// out = (sum_bn min_m d2 + sum_bm min_n d2) / 32768
//
// Round 8: r3 post-mortem — DS-broadcast sweep REGRESSED (59.7us, busy 47%):
// 4x ds_read_b64/record loads the shared DS pipe + coarse lgkm waits beat
// the kernel harder than the SMEM convoy did. SMEM version (44.8us, busy
// 64%) stalls 36% at only 4 waves/SIMD (2 blocks/CU). Fixed ~46us/iter
// harness overhead is untouchable; minimize kernel time.
// SMEM dbuf sweep (r1-verified code) + 8 waves/SIMD (1024 blocks, S=8
// segs, 64 rec/wave, 4 blocks/CU co-resident) + wave-staggered sweep
// order to break the scalar-return convoy. Sum kernel fused into chamfer
// via r3-verified fence+counter finalize.
// Round 9 (this round): infra timeout, kernel never ran. Cold re-audit
// passed (indexing, stagger bijection, alignment, protocol); one noted
// risk: SGPR alloc ~112/wave may cap at 7 waves/SIMD instead of 8 —
// acceptable. Resubmitting unchanged.
// Predicted: chamfer ~30us @ VALUBusy ~80%; total ~82us.

#define N_      8192
#define RPB     4096          // records (2 points) per batch per side
#define NRECS   16384         // records per side
#define NGRP    128           // (dir,batch,qg) groups of 512 queries
#define FLT_BIG 3.0e38f

typedef float v2f  __attribute__((ext_vector_type(2)));
typedef unsigned int v16u __attribute__((ext_vector_type(16)));

__global__ void zero_out_kernel(float* out) { *out = 0.0f; }

// ---------------- prep: pack pair-records ----------------
// record r of a side: dst[2r]={x0,x1,y0,y1}, dst[2r+1]={z0,z1,w0,w1}
__global__ __launch_bounds__(256) void prep_kernel(
    const float* __restrict__ x, const float* __restrict__ y,
    float4* __restrict__ xrec, float4* __restrict__ yrec)
{
    int i = blockIdx.x * 256 + threadIdx.x;   // 0..32767
    int side = i >> 14;
    int r    = i & (NRECS - 1);
    const float* src = side ? y : x;
    float4*      dst = side ? yrec : xrec;
    const float* p = src + (size_t)r * 6;
    float p0x = p[0], p0y = p[1], p0z = p[2];
    float p1x = p[3], p1y = p[4], p1z = p[5];
    float w0 = fmaf(p0x, p0x, fmaf(p0y, p0y, p0z * p0z));
    float w1 = fmaf(p1x, p1x, fmaf(p1y, p1y, p1z * p1z));
    dst[2*r]   = make_float4(p0x, p1x, p0y, p1y);
    dst[2*r+1] = make_float4(p0z, p1z, w0, w1);
}

// ---------------- main ----------------
static __device__ __forceinline__ void s_load2(v16u& a, v16u& b, const unsigned int* p) {
    asm volatile("s_load_dwordx16 %0, %2, 0x0\n\t"
                 "s_load_dwordx16 %1, %2, 0x40"
                 : "=s"(a), "=s"(b) : "s"(p));
}
static __device__ __forceinline__ void s_wait(v16u& a, v16u& b) {
    asm volatile("s_waitcnt lgkmcnt(0)" : "+s"(a), "+s"(b));
}

// one record (8 uniform dwords, mostly SGPR operands) vs 4 query-pairs
static __device__ __forceinline__ void do_record(
    const unsigned int* d,
    const v2f* qx, const v2f* qy, const v2f* qz,  // -2 prescaled
    float* acc)
{
    v2f pxs = (v2f){__uint_as_float(d[0]), __uint_as_float(d[1])};
    v2f pys = (v2f){__uint_as_float(d[2]), __uint_as_float(d[3])};
    v2f pzs = (v2f){__uint_as_float(d[4]), __uint_as_float(d[5])};
    v2f w2v = (v2f){__uint_as_float(d[6]), __uint_as_float(d[7])};  // -> VGPR pair
    #pragma unroll
    for (int j = 0; j < 4; ++j) {
        v2f td, ts;
        // td = {q0*p0, q1*p1} chain; ts = {q0*p1, q1*p0} via op_sel swap
        asm("v_pk_fma_f32 %0, %1, %2, %3"
            : "=v"(td) : "v"(qz[j]), "s"(pzs), "v"(w2v));
        asm("v_pk_fma_f32 %0, %1, %2, %3 op_sel:[0,1,1] op_sel_hi:[1,0,0]"
            : "=v"(ts) : "v"(qz[j]), "s"(pzs), "v"(w2v));
        asm("v_pk_fma_f32 %0, %1, %2, %0"
            : "+v"(td) : "v"(qy[j]), "s"(pys));
        asm("v_pk_fma_f32 %0, %1, %2, %0 op_sel:[0,1,0] op_sel_hi:[1,0,1]"
            : "+v"(ts) : "v"(qy[j]), "s"(pys));
        asm("v_pk_fma_f32 %0, %1, %2, %0"
            : "+v"(td) : "v"(qx[j]), "s"(pxs));
        asm("v_pk_fma_f32 %0, %1, %2, %0 op_sel:[0,1,0] op_sel_hi:[1,0,1]"
            : "+v"(ts) : "v"(qx[j]), "s"(pxs));
        asm("v_min3_f32 %0, %0, %1, %2" : "+v"(acc[2*j])   : "v"(td.x), "v"(ts.x));
        asm("v_min3_f32 %0, %0, %1, %2" : "+v"(acc[2*j+1]) : "v"(td.y), "v"(ts.y));
    }
}

// 1024 blocks x 512 thr (8 waves). Block = (dir, batch, qgroup of 512 q,
// seg of 512 records). Wave sweeps 64 records (16 load-groups of 4, dbuf,
// wave-staggered order). 4 blocks/CU -> 8 waves/SIMD.
__global__ __launch_bounds__(512, 8) void chamfer_kernel(
    const float* __restrict__ xraw, const float* __restrict__ yraw,
    const float4* __restrict__ xrec, const float4* __restrict__ yrec,
    float* __restrict__ partial,        // [NGRP][8 seg][512 q]
    unsigned int* __restrict__ ctrl,    // [NGRP cnt][1 fcnt][1 accum(float)]
    float* __restrict__ out)
{
    __shared__ float red[8 * 512];      // 16 KB
    __shared__ unsigned int sflag;

    const int tid  = threadIdx.x;
    const int lane = tid & 63;
    const int wave = __builtin_amdgcn_readfirstlane(tid >> 6);
    const int blk  = blockIdx.x;        // 0..1023
    const int dir   = blk >> 9;
    const int batch = (blk >> 7) & 3;
    const int qg    = (blk >> 3) & 15;
    const int seg   = blk & 7;
    const int g     = blk >> 3;         // group 0..127

    const float*  qraw = dir ? yraw : xraw;
    const float4* orec = dir ? xrec : yrec;

    // ---- load this lane's 8 queries (contiguous 24 floats, 16B-aligned) ----
    const int qbase = batch * N_ + qg * 512;
    float f[24];
    {
        const float4* qv = (const float4*)(qraw + (size_t)qbase * 3) + lane * 6;
        #pragma unroll
        for (int k = 0; k < 6; ++k) {
            float4 t = qv[k];
            f[4*k] = t.x; f[4*k+1] = t.y; f[4*k+2] = t.z; f[4*k+3] = t.w;
        }
    }
    v2f qx[4], qy[4], qz[4];
    float acc[8];
    #pragma unroll
    for (int j = 0; j < 4; ++j) {
        qx[j] = (v2f){-2.0f * f[6*j+0], -2.0f * f[6*j+3]};
        qy[j] = (v2f){-2.0f * f[6*j+1], -2.0f * f[6*j+4]};
        qz[j] = (v2f){-2.0f * f[6*j+2], -2.0f * f[6*j+5]};
        acc[2*j] = FLT_BIG; acc[2*j+1] = FLT_BIG;
    }

    // ---- SMEM dbuf sweep: 64 records = 16 groups of 4 (2x dwordx16 each),
    //      wave-staggered visiting order (min is order-independent) ----
    const unsigned int* sp = (const unsigned int*)
        (orec + (size_t)2 * (batch * RPB + seg * 512 + wave * 64));
    const int off = wave * 2;
    v16u a0, a1, b0, b1;
    s_load2(a0, a1, sp + ((0 + off) & 15) * 32);
    for (int i = 0; i < 16; i += 2) {
        s_wait(a0, a1);
        s_load2(b0, b1, sp + (((i + 1) + off) & 15) * 32);
        {
            unsigned int da[16], db[16];
            #pragma unroll
            for (int t = 0; t < 16; ++t) { da[t] = a0[t]; db[t] = a1[t]; }
            do_record(da,     qx, qy, qz, acc);
            do_record(da + 8, qx, qy, qz, acc);
            do_record(db,     qx, qy, qz, acc);
            do_record(db + 8, qx, qy, qz, acc);
        }
        s_wait(b0, b1);
        if (i + 2 < 16) s_load2(a0, a1, sp + (((i + 2) + off) & 15) * 32);
        {
            unsigned int da[16], db[16];
            #pragma unroll
            for (int t = 0; t < 16; ++t) { da[t] = b0[t]; db[t] = b1[t]; }
            do_record(da,     qx, qy, qz, acc);
            do_record(da + 8, qx, qy, qz, acc);
            do_record(db,     qx, qy, qz, acc);
            do_record(db + 8, qx, qy, qz, acc);
        }
    }

    // ---- block combine: 8 wave-partials per query ----
    #pragma unroll
    for (int j = 0; j < 8; ++j) red[wave * 512 + lane * 8 + j] = acc[j];
    __syncthreads();
    float m = red[tid];                          // thread t owns query qbase+t
    #pragma unroll
    for (int w = 1; w < 8; ++w) m = fminf(m, red[w * 512 + tid]);

    // ---- per-seg partial min -> ws (plain store; r3-verified protocol) ----
    partial[((size_t)g * 8 + seg) * 512 + tid] = m;
    __syncthreads();
    if (tid == 0) {
        __threadfence();                         // release partial stores
        sflag = atomicAdd(&ctrl[g], 1u);
    }
    __syncthreads();
    if (sflag == 7u) {                           // last seg-block: finalize group
        if (tid == 0) __threadfence();           // acquire others' partials
        __syncthreads();
        const float* pg = partial + (size_t)g * 8 * 512;
        float mm = pg[tid];
        #pragma unroll
        for (int s = 1; s < 8; ++s) mm = fminf(mm, pg[s * 512 + tid]);
        int gq = qbase + tid;
        float ax = qraw[gq*3+0], ay = qraw[gq*3+1], az = qraw[gq*3+2];
        float qn = fmaf(ax, ax, fmaf(ay, ay, az * az));
        float d2 = fmaxf(0.0f, qn + mm);         // relu commutes with min
        #pragma unroll
        for (int o = 32; o > 0; o >>= 1) d2 += __shfl_xor(d2, o);
        if (lane == 0) red[wave] = d2;
        __syncthreads();
        if (tid == 0) {
            float s = red[0];
            #pragma unroll
            for (int w = 1; w < 8; ++w) s += red[w];
            atomicAdd((float*)&ctrl[NGRP + 1], s * (1.0f / 32768.0f));
            __threadfence();
            unsigned int o2 = atomicAdd(&ctrl[NGRP], 1u);
            if (o2 == (unsigned)(NGRP - 1)) {    // last group: publish
                float tot = atomicAdd((float*)&ctrl[NGRP + 1], 0.0f);
                *out = tot;
            }
        }
    }
}

// ---------------- fallback (ws too small): round-1 kernel ----------------
__global__ __launch_bounds__(1024) void chamfer_raw_kernel(
    const float* __restrict__ xraw, const float* __restrict__ yraw,
    float* __restrict__ out)
{
    __shared__ float4 red4[16][64];
    const int tid  = threadIdx.x;
    const int wave = tid >> 6;
    const int lane = tid & 63;
    const int blk  = blockIdx.x;
    const bool xdir = (blk < 128);
    const int b    = (blk & 127) >> 5;
    const int qofs = (blk & 31) << 8;
    const float* qraw = xdir ? xraw : yraw;
    const float* oraw = xdir ? yraw : xraw;
    float qx0[4], qx1[4], qx2[4], acc[4];
    #pragma unroll
    for (int q = 0; q < 4; ++q) {
        int gq = b * N_ + qofs + lane*4 + q;
        qx0[q] = qraw[gq*3+0]; qx1[q] = qraw[gq*3+1]; qx2[q] = qraw[gq*3+2];
        acc[q] = FLT_BIG;
    }
    const float* opp = oraw + (size_t)(b * N_ + wave * 512) * 3;
    #pragma unroll 4
    for (int k = 0; k < 512; ++k) {
        float p0 = opp[k*3+0], p1 = opp[k*3+1], p2 = opp[k*3+2];
        float w  = fmaf(p0, p0, fmaf(p1, p1, p2*p2));
        #pragma unroll
        for (int q = 0; q < 4; ++q) {
            float dot = qx0[q]*p0 + qx1[q]*p1 + qx2[q]*p2;
            acc[q] = fminf(acc[q], fmaf(-2.0f, dot, w));
        }
    }
    red4[wave][lane] = make_float4(acc[0], acc[1], acc[2], acc[3]);
    __syncthreads();
    if (tid < 256) {
        const float* red = (const float*)red4;
        float m = red[tid];
        #pragma unroll
        for (int w = 1; w < 16; ++w) m = fminf(m, red[w*256 + tid]);
        int gq = b * N_ + qofs + tid;
        float ax = qraw[gq*3+0], ay = qraw[gq*3+1], az = qraw[gq*3+2];
        float d2 = fmaxf(0.0f, fmaf(ax,ax,fmaf(ay,ay,az*az)) + m);
        #pragma unroll
        for (int off = 32; off > 0; off >>= 1) d2 += __shfl_xor(d2, off);
        if ((tid & 63) == 0) atomicAdd(out, d2 * (1.0f / 32768.0f));
    }
}

extern "C" void kernel_launch(void* const* d_in, const int* in_sizes, int n_in,
                              void* d_out, int out_size, void* d_ws, size_t ws_size,
                              hipStream_t stream)
{
    const float* x = (const float*)d_in[0];
    const float* y = (const float*)d_in[1];
    float* out = (float*)d_out;

    // ws layout: [0,512K) xrec, [512K,1M) yrec, [1M,3M) partial, then ctrl
    const size_t recs_b    = (size_t)NRECS * 2 * 2 * sizeof(float4); // 1 MB
    const size_t partial_b = (size_t)NGRP * 8 * 512 * sizeof(float); // 2 MB
    const size_t need = recs_b + partial_b + (NGRP + 2) * 4;
    if (ws_size >= need) {
        float4* xrec = (float4*)d_ws;
        float4* yrec = xrec + 2 * NRECS;
        float*  partial = (float*)(yrec + 2 * NRECS);
        unsigned int* ctrl = (unsigned int*)(partial + (size_t)NGRP * 8 * 512);
        hipMemsetAsync(ctrl, 0, (NGRP + 2) * 4, stream);
        prep_kernel<<<128, 256, 0, stream>>>(x, y, xrec, yrec);
        chamfer_kernel<<<1024, 512, 0, stream>>>(x, y, xrec, yrec, partial, ctrl, out);
    } else {
        zero_out_kernel<<<1, 1, 0, stream>>>(out);
        chamfer_raw_kernel<<<256, 1024, 0, stream>>>(x, y, out);
    }
}

// Round 7
// 111.246 us; speedup vs baseline: 1.2292x; 1.2292x over previous
//
#include <hip/hip_runtime.h>

// ChamferLoss: x,y [4, 8192, 3] fp32 -> scalar fp32.
// out = (sum_bn min_m d2 + sum_bm min_n d2) / 32768
//
// Round 10: r5 post-mortem — 8 waves/SIMD SMEM REGRESSED (87us, busy 33%);
// VALU-busy time is invariant at 28.7us across r1/r3/r5 while stalls grew.
// All shared-pipe record-delivery paths measured and all stall:
//   SMEM s_load (r1: 36% stall), DS broadcast (r3: 53%), SMEM@2x waves
//   (r5: 67%). => remove memory from the inner loop entirely.
// Systolic register rotation: lane holds one pair-record in 8 VGPRs
// (rows duplicate a 16-record ring); ring rotates via v_mov_dpp row_ror:1
// (8 movs/step, pure VALU, no waits). Reload = 3 coalesced float2 loads
// per lane per 16 steps (latency trivially hidden). Prep kernel gone
// (lanes pack their own records + w in-lane). Finalize = r3-verified
// fence+counter protocol (4 segs).
// Round 11 (this round): infra timeout again, kernel never ran. Cold
// re-audit passed (DPP ctrl 0x121=row_ror:1 encoding + arg order, ring
// bijection, record coverage, red-index algebra, prefetch ordering,
// protocol). Resubmitting unchanged.
// Model: 128 cyc per record per wave -> ~31us busy, ~33-36us duration.
// Predicted: VALUBusy >=85%, SGPR ~32, total ~80us.

#define N_      8192
#define RPB     4096          // pair-records per batch per side
#define NGRP    128           // (dir,batch,qg) groups of 512 queries
#define FLT_BIG 3.0e38f

typedef float v2f __attribute__((ext_vector_type(2)));

__global__ void zero_out_kernel(float* out) { *out = 0.0f; }

// rotate one VGPR right by 1 lane within each 16-lane row (DPP row_ror:1)
static __device__ __forceinline__ float rot16(float v) {
    return __uint_as_float((unsigned)__builtin_amdgcn_update_dpp(
        0, (int)__float_as_uint(v), 0x121, 0xf, 0xf, true));
}
static __device__ __forceinline__ v2f rot16v(v2f v) {
    v2f r; r.x = rot16(v.x); r.y = rot16(v.y); return r;
}

// one pair-record (VGPR pairs) vs 4 query-pairs; q pre-scaled by -2.
// td = {v(q0,p0), v(q1,p1)}; ts = {v(q0,p1), v(q1,p0)}; v = w_p - 2 q.p
static __device__ __forceinline__ void do_record_v(
    v2f pxs, v2f pys, v2f pzs, v2f wv,
    const v2f* qx, const v2f* qy, const v2f* qz,
    float* acc)
{
    #pragma unroll
    for (int j = 0; j < 4; ++j) {
        v2f td, ts;
        asm("v_pk_fma_f32 %0, %1, %2, %3"
            : "=v"(td) : "v"(qz[j]), "v"(pzs), "v"(wv));
        asm("v_pk_fma_f32 %0, %1, %2, %3 op_sel:[0,1,1] op_sel_hi:[1,0,0]"
            : "=v"(ts) : "v"(qz[j]), "v"(pzs), "v"(wv));
        asm("v_pk_fma_f32 %0, %1, %2, %0"
            : "+v"(td) : "v"(qy[j]), "v"(pys));
        asm("v_pk_fma_f32 %0, %1, %2, %0 op_sel:[0,1,0] op_sel_hi:[1,0,1]"
            : "+v"(ts) : "v"(qy[j]), "v"(pys));
        asm("v_pk_fma_f32 %0, %1, %2, %0"
            : "+v"(td) : "v"(qx[j]), "v"(pxs));
        asm("v_pk_fma_f32 %0, %1, %2, %0 op_sel:[0,1,0] op_sel_hi:[1,0,1]"
            : "+v"(ts) : "v"(qx[j]), "v"(pxs));
        asm("v_min3_f32 %0, %0, %1, %2" : "+v"(acc[2*j])   : "v"(td.x), "v"(ts.x));
        asm("v_min3_f32 %0, %0, %1, %2" : "+v"(acc[2*j+1]) : "v"(td.y), "v"(ts.y));
    }
}

// 512 blocks x 512 thr (8 waves). Block = (dir, batch, qgroup of 512 q,
// seg of 1024 records). Wave sweeps 128 records = 8 ring-fills of 16.
__global__ __launch_bounds__(512, 4) void chamfer_kernel(
    const float* __restrict__ xraw, const float* __restrict__ yraw,
    float* __restrict__ partial,        // [NGRP][4 seg][512 q]
    unsigned int* __restrict__ ctrl,    // [NGRP cnt][1 fcnt][1 accum(float)]
    float* __restrict__ out)
{
    __shared__ float red[8 * 512];      // 16 KB
    __shared__ unsigned int sflag;

    const int tid  = threadIdx.x;
    const int lane = tid & 63;
    const int wave = __builtin_amdgcn_readfirstlane(tid >> 6);
    const int blk  = blockIdx.x;        // 0..511
    const int dir   = blk >> 8;
    const int batch = (blk >> 6) & 3;
    const int qg    = (blk >> 2) & 15;
    const int seg   = blk & 3;
    const int g     = blk >> 2;         // group 0..127

    const float* qraw = dir ? yraw : xraw;
    const float* oraw = dir ? xraw : yraw;

    // ---- load this lane's 8 queries (contiguous 24 floats, 16B-aligned) ----
    const int qbase = batch * N_ + qg * 512;
    float f[24];
    {
        const float4* qv = (const float4*)(qraw + (size_t)qbase * 3) + lane * 6;
        #pragma unroll
        for (int k = 0; k < 6; ++k) {
            float4 t = qv[k];
            f[4*k] = t.x; f[4*k+1] = t.y; f[4*k+2] = t.z; f[4*k+3] = t.w;
        }
    }
    v2f qx[4], qy[4], qz[4];
    float acc[8];
    #pragma unroll
    for (int j = 0; j < 4; ++j) {
        qx[j] = (v2f){-2.0f * f[6*j+0], -2.0f * f[6*j+3]};
        qy[j] = (v2f){-2.0f * f[6*j+1], -2.0f * f[6*j+4]};
        qz[j] = (v2f){-2.0f * f[6*j+2], -2.0f * f[6*j+5]};
        acc[2*j] = FLT_BIG; acc[2*j+1] = FLT_BIG;
    }

    // ---- systolic sweep: 128 records = 8 ring-fills of 16 ----
    // lane's ring slot: record rbase + fill*16 + (lane&15); rows duplicate.
    // raw pair-record r = floats [6r, 6r+6) = 3x float2 (8B aligned).
    const float2* rp = (const float2*)
        (oraw + (size_t)(batch * RPB + seg * 1024 + wave * 128 + (lane & 15)) * 6);
    float2 A = rp[0], Bv = rp[1], Cv = rp[2];
    #pragma unroll 1
    for (int fl = 0; fl < 8; ++fl) {
        // pack pending raw -> ring regs; w = |p|^2 per point
        v2f pxs = (v2f){A.x,  Bv.y};
        v2f pys = (v2f){A.y,  Cv.x};
        v2f pzs = (v2f){Bv.x, Cv.y};
        v2f wv;
        wv.x = fmaf(A.x,  A.x,  fmaf(A.y,  A.y,  Bv.x * Bv.x));
        wv.y = fmaf(Bv.y, Bv.y, fmaf(Cv.x, Cv.x, Cv.y * Cv.y));
        if (fl < 7) {                    // prefetch next fill (16 recs = 48 float2)
            const float2* np = rp + (fl + 1) * 48;
            A = np[0]; Bv = np[1]; Cv = np[2];
        }
        #pragma unroll
        for (int s = 0; s < 16; ++s) {
            if (s) {
                pxs = rot16v(pxs); pys = rot16v(pys);
                pzs = rot16v(pzs); wv  = rot16v(wv);
            }
            do_record_v(pxs, pys, pzs, wv, qx, qy, qz, acc);
        }
    }

    // ---- block combine: 8 wave-partials per query ----
    #pragma unroll
    for (int j = 0; j < 8; ++j) red[wave * 512 + lane * 8 + j] = acc[j];
    __syncthreads();
    float m = red[tid];                          // thread t owns query qbase+t
    #pragma unroll
    for (int w = 1; w < 8; ++w) m = fminf(m, red[w * 512 + tid]);

    // ---- per-seg partial min -> ws (r3-verified protocol, 4 segs) ----
    partial[((size_t)g * 4 + seg) * 512 + tid] = m;
    __syncthreads();
    if (tid == 0) {
        __threadfence();                         // release partial stores
        sflag = atomicAdd(&ctrl[g], 1u);
    }
    __syncthreads();
    if (sflag == 3u) {                           // last seg-block: finalize group
        if (tid == 0) __threadfence();           // acquire others' partials
        __syncthreads();
        const float* pg = partial + (size_t)g * 4 * 512;
        float mm = fminf(fminf(pg[tid], pg[512 + tid]),
                         fminf(pg[1024 + tid], pg[1536 + tid]));
        int gq = qbase + tid;
        float ax = qraw[gq*3+0], ay = qraw[gq*3+1], az = qraw[gq*3+2];
        float qn = fmaf(ax, ax, fmaf(ay, ay, az * az));
        float d2 = fmaxf(0.0f, qn + mm);         // relu commutes with min
        #pragma unroll
        for (int o = 32; o > 0; o >>= 1) d2 += __shfl_xor(d2, o);
        if (lane == 0) red[wave] = d2;
        __syncthreads();
        if (tid == 0) {
            float s = red[0];
            #pragma unroll
            for (int w = 1; w < 8; ++w) s += red[w];
            atomicAdd((float*)&ctrl[NGRP + 1], s * (1.0f / 32768.0f));
            __threadfence();
            unsigned int o2 = atomicAdd(&ctrl[NGRP], 1u);
            if (o2 == (unsigned)(NGRP - 1)) {    // last group: publish
                float tot = atomicAdd((float*)&ctrl[NGRP + 1], 0.0f);
                *out = tot;
            }
        }
    }
}

// ---------------- fallback (ws too small): round-1 kernel ----------------
__global__ __launch_bounds__(1024) void chamfer_raw_kernel(
    const float* __restrict__ xraw, const float* __restrict__ yraw,
    float* __restrict__ out)
{
    __shared__ float4 red4[16][64];
    const int tid  = threadIdx.x;
    const int wave = tid >> 6;
    const int lane = tid & 63;
    const int blk  = blockIdx.x;
    const bool xdir = (blk < 128);
    const int b    = (blk & 127) >> 5;
    const int qofs = (blk & 31) << 8;
    const float* qraw = xdir ? xraw : yraw;
    const float* oraw = xdir ? yraw : xraw;
    float qx0[4], qx1[4], qx2[4], acc[4];
    #pragma unroll
    for (int q = 0; q < 4; ++q) {
        int gq = b * N_ + qofs + lane*4 + q;
        qx0[q] = qraw[gq*3+0]; qx1[q] = qraw[gq*3+1]; qx2[q] = qraw[gq*3+2];
        acc[q] = FLT_BIG;
    }
    const float* opp = oraw + (size_t)(b * N_ + wave * 512) * 3;
    #pragma unroll 4
    for (int k = 0; k < 512; ++k) {
        float p0 = opp[k*3+0], p1 = opp[k*3+1], p2 = opp[k*3+2];
        float w  = fmaf(p0, p0, fmaf(p1, p1, p2*p2));
        #pragma unroll
        for (int q = 0; q < 4; ++q) {
            float dot = qx0[q]*p0 + qx1[q]*p1 + qx2[q]*p2;
            acc[q] = fminf(acc[q], fmaf(-2.0f, dot, w));
        }
    }
    red4[wave][lane] = make_float4(acc[0], acc[1], acc[2], acc[3]);
    __syncthreads();
    if (tid < 256) {
        const float* red = (const float*)red4;
        float m = red[tid];
        #pragma unroll
        for (int w = 1; w < 16; ++w) m = fminf(m, red[w*256 + tid]);
        int gq = b * N_ + qofs + tid;
        float ax = qraw[gq*3+0], ay = qraw[gq*3+1], az = qraw[gq*3+2];
        float d2 = fmaxf(0.0f, fmaf(ax,ax,fmaf(ay,ay,az*az)) + m);
        #pragma unroll
        for (int off = 32; off > 0; off >>= 1) d2 += __shfl_xor(d2, off);
        if ((tid & 63) == 0) atomicAdd(out, d2 * (1.0f / 32768.0f));
    }
}

extern "C" void kernel_launch(void* const* d_in, const int* in_sizes, int n_in,
                              void* d_out, int out_size, void* d_ws, size_t ws_size,
                              hipStream_t stream)
{
    const float* x = (const float*)d_in[0];
    const float* y = (const float*)d_in[1];
    float* out = (float*)d_out;

    // ws layout: [0,1M) partial mins [128][4][512] f32, then ctrl[130] u32
    const size_t need = (size_t)NGRP * 4 * 512 * sizeof(float) + (NGRP + 2) * 4;
    if (ws_size >= need) {
        float* partial = (float*)d_ws;
        unsigned int* ctrl = (unsigned int*)(partial + (size_t)NGRP * 4 * 512);
        hipMemsetAsync(ctrl, 0, (NGRP + 2) * 4, stream);
        chamfer_kernel<<<512, 512, 0, stream>>>(x, y, partial, ctrl, out);
    } else {
        zero_out_kernel<<<1, 1, 0, stream>>>(out);
        chamfer_raw_kernel<<<256, 1024, 0, stream>>>(x, y, out);
    }
}

// Round 9
// 97.612 us; speedup vs baseline: 1.4009x; 1.1397x over previous
//
#include <hip/hip_runtime.h>

// ChamferLoss: x,y [4, 8192, 3] fp32 -> scalar fp32.
// out = (sum_bn min_m d2 + sum_bm min_n d2) / 32768
//
// Round 12: r7 post-mortem — systolic sweep's busy matched model (34us)
// but stall 28us: ~12us is the fence+counter finalize (device-scope
// threadfence = XCD L2 writeback on critical path), rest is launch
// ramp/drain (present in both SMEM r1 and register r7 => NOT delivery).
// Symmetric systolic: the rotating record carries a COLUMN accumulator,
// so each unique pair-cell is computed ONCE and feeds both chamfer
// directions (row-min for x-queries in lane accs, col-min for y-points
// riding the ring). Halves the sweep: 256 blocks (1/CU), one direction.
// 180 cyc/record for both dirs vs 2x128 before. Col path: relu -> LDS
// colbuf per fill -> atomicMin burst at block end. Row path: r1-verified
// relu(qn+min) atomicMin epilogue. No fences; r1-verified sum_kernel.
// Round 13 (this round): infra timeout, never ran. Audit found an
// OFF-BY-ONE in the col path: the 16-step loop rotates only 15 times, so
// cacc ends one lane away from its record's home; colbuf then misassigns
// col-mins to neighboring y-points. Fix: one extra rot16v(cacc) after the
// loop (15+1=16 == identity mod 16 — correct for EITHER ror direction).
// Model: ~47K cyc/SIMD = ~20us busy. Predicted: chamfer 34-40us,
// VALUBusy 55-65%, total ~85-90us.

#define N_      8192
#define RPB     4096          // pair-records per batch (y side)
#define FLT_BIG 3.0e38f

typedef float v2f __attribute__((ext_vector_type(2)));

__global__ void zero_out_kernel(float* out) { *out = 0.0f; }

// rotate one VGPR by 1 lane within each 16-lane row (DPP row_ror:1)
static __device__ __forceinline__ float rot16(float v) {
    return __uint_as_float((unsigned)__builtin_amdgcn_update_dpp(
        0, (int)__float_as_uint(v), 0x121, 0xf, 0xf, true));
}
static __device__ __forceinline__ v2f rot16v(v2f v) {
    v2f r; r.x = rot16(v.x); r.y = rot16(v.y); return r;
}

// one pair-record vs 4 query-pairs, BOTH directions.
// v = w_p - 2 q.p ; row keeps v (qn added in epilogue);
// col needs full d2 = v + qn_q (qn uncrossed: same qnv for td and ts).
// td = {v(q0,p0), v(q1,p1)}; ts = {v(q0,p1), v(q1,p0)}.
static __device__ __forceinline__ void do_record_sym(
    v2f pxs, v2f pys, v2f pzs, v2f wv,
    const v2f* qx, const v2f* qy, const v2f* qz, const v2f* qnv,
    float* acc, v2f* cacc)
{
    #pragma unroll
    for (int j = 0; j < 4; ++j) {
        v2f td, ts;
        asm("v_pk_fma_f32 %0, %1, %2, %3"
            : "=v"(td) : "v"(qz[j]), "v"(pzs), "v"(wv));
        asm("v_pk_fma_f32 %0, %1, %2, %3 op_sel:[0,1,1] op_sel_hi:[1,0,0]"
            : "=v"(ts) : "v"(qz[j]), "v"(pzs), "v"(wv));
        asm("v_pk_fma_f32 %0, %1, %2, %0"
            : "+v"(td) : "v"(qy[j]), "v"(pys));
        asm("v_pk_fma_f32 %0, %1, %2, %0 op_sel:[0,1,0] op_sel_hi:[1,0,1]"
            : "+v"(ts) : "v"(qy[j]), "v"(pys));
        asm("v_pk_fma_f32 %0, %1, %2, %0"
            : "+v"(td) : "v"(qx[j]), "v"(pxs));
        asm("v_pk_fma_f32 %0, %1, %2, %0 op_sel:[0,1,0] op_sel_hi:[1,0,1]"
            : "+v"(ts) : "v"(qx[j]), "v"(pxs));
        // row mins (x-queries), qn excluded
        asm("v_min3_f32 %0, %0, %1, %2" : "+v"(acc[2*j])   : "v"(td.x), "v"(ts.x));
        asm("v_min3_f32 %0, %0, %1, %2" : "+v"(acc[2*j+1]) : "v"(td.y), "v"(ts.y));
        // col mins (y-points), full d2: + qn (uncrossed; p0 cells are td.x,ts.y)
        v2f tdq, tsq;
        asm("v_pk_add_f32 %0, %1, %2" : "=v"(tdq) : "v"(td), "v"(qnv[j]));
        asm("v_pk_add_f32 %0, %1, %2" : "=v"(tsq) : "v"(ts), "v"(qnv[j]));
        asm("v_min3_f32 %0, %0, %1, %2" : "+v"(cacc->x) : "v"(tdq.x), "v"(tsq.y));
        asm("v_min3_f32 %0, %0, %1, %2" : "+v"(cacc->y) : "v"(tsq.x), "v"(tdq.y));
    }
}

// 256 blocks x 512 thr (8 waves), 1 block/CU. Block = (batch, qgroup of
// 512 x-queries, seg of 1024 y-records). Wave sweeps 128 records = 8
// ring-fills of 16; each unique cell feeds both directions.
__global__ __launch_bounds__(512, 4) void chamfer_kernel(
    const float* __restrict__ xraw, const float* __restrict__ yraw,
    unsigned int* __restrict__ pmin)    // [2][4][8192]: x-side then y-side
{
    __shared__ float red[8 * 512];      // 16 KB (row combine)
    __shared__ float colbuf[8][256];    // 8 KB  (per-wave col mins)

    const int tid  = threadIdx.x;
    const int lane = tid & 63;
    const int wave = __builtin_amdgcn_readfirstlane(tid >> 6);
    const int blk  = blockIdx.x;        // 0..255
    const int batch = blk >> 6;
    const int qg    = (blk >> 2) & 15;
    const int seg   = blk & 3;

    // ---- load this lane's 8 x-queries (24 floats, 16B-aligned) ----
    const int qbase = batch * N_ + qg * 512;
    float f[24];
    {
        const float4* qv = (const float4*)(xraw + (size_t)qbase * 3) + lane * 6;
        #pragma unroll
        for (int k = 0; k < 6; ++k) {
            float4 t = qv[k];
            f[4*k] = t.x; f[4*k+1] = t.y; f[4*k+2] = t.z; f[4*k+3] = t.w;
        }
    }
    v2f qx[4], qy[4], qz[4], qnv[4];
    float acc[8];
    #pragma unroll
    for (int j = 0; j < 4; ++j) {
        qnv[j].x = fmaf(f[6*j+0], f[6*j+0],
                   fmaf(f[6*j+1], f[6*j+1], f[6*j+2] * f[6*j+2]));
        qnv[j].y = fmaf(f[6*j+3], f[6*j+3],
                   fmaf(f[6*j+4], f[6*j+4], f[6*j+5] * f[6*j+5]));
        qx[j] = (v2f){-2.0f * f[6*j+0], -2.0f * f[6*j+3]};
        qy[j] = (v2f){-2.0f * f[6*j+1], -2.0f * f[6*j+4]};
        qz[j] = (v2f){-2.0f * f[6*j+2], -2.0f * f[6*j+5]};
        acc[2*j] = FLT_BIG; acc[2*j+1] = FLT_BIG;
    }

    // ---- symmetric systolic sweep: 128 y-records = 8 ring-fills of 16 ----
    const int rbase = seg * 1024 + wave * 128;    // wave's record base in batch
    const float2* rp = (const float2*)
        (yraw + (size_t)(batch * RPB + rbase + (lane & 15)) * 6);
    float2 A = rp[0], Bv = rp[1], Cv = rp[2];
    #pragma unroll 1
    for (int fl = 0; fl < 8; ++fl) {
        v2f pxs = (v2f){A.x,  Bv.y};
        v2f pys = (v2f){A.y,  Cv.x};
        v2f pzs = (v2f){Bv.x, Cv.y};
        v2f wv;
        wv.x = fmaf(A.x,  A.x,  fmaf(A.y,  A.y,  Bv.x * Bv.x));
        wv.y = fmaf(Bv.y, Bv.y, fmaf(Cv.x, Cv.x, Cv.y * Cv.y));
        if (fl < 7) {                    // prefetch next fill (16 recs = 48 float2)
            const float2* np = rp + (fl + 1) * 48;
            A = np[0]; Bv = np[1]; Cv = np[2];
        }
        v2f cacc = (v2f){FLT_BIG, FLT_BIG};
        #pragma unroll
        for (int s = 0; s < 16; ++s) {
            if (s) {
                pxs = rot16v(pxs); pys = rot16v(pys);
                pzs = rot16v(pzs); wv  = rot16v(wv);
                cacc = rot16v(cacc);     // col acc rides its record
            }
            do_record_sym(pxs, pys, pzs, wv, qx, qy, qz, qnv, acc, &cacc);
        }
        // 15 rotations happened; one more returns cacc to its record's
        // home lane (16 == identity, valid for either ror direction).
        cacc = rot16v(cacc);
        // fold the 4 duplicate rows, relu, stash in LDS.
        cacc.x = fminf(cacc.x, __shfl_xor(cacc.x, 16));
        cacc.x = fminf(cacc.x, __shfl_xor(cacc.x, 32));
        cacc.y = fminf(cacc.y, __shfl_xor(cacc.y, 16));
        cacc.y = fminf(cacc.y, __shfl_xor(cacc.y, 32));
        if (lane < 16) {
            colbuf[wave][fl * 32 + lane * 2]     = fmaxf(0.0f, cacc.x);
            colbuf[wave][fl * 32 + lane * 2 + 1] = fmaxf(0.0f, cacc.y);
        }
    }

    // ---- col epilogue: wave's 256 col-mins -> global atomicMin ----
    {
        unsigned int* py = pmin + 32768 + batch * N_ + 2 * rbase;
        #pragma unroll
        for (int k = 0; k < 4; ++k) {
            int idx = lane * 4 + k;              // 0..255
            float v = colbuf[wave][idx];
            atomicMin(&py[idx], __float_as_uint(v));
        }
    }

    // ---- row epilogue: block combine + relu(qn+min) -> atomicMin ----
    #pragma unroll
    for (int j = 0; j < 8; ++j) red[wave * 512 + lane * 8 + j] = acc[j];
    __syncthreads();
    float m = red[tid];                          // thread t owns query qbase+t
    #pragma unroll
    for (int w = 1; w < 8; ++w) m = fminf(m, red[w * 512 + tid]);
    int gq = qbase + tid;
    float ax = xraw[gq*3+0], ay = xraw[gq*3+1], az = xraw[gq*3+2];
    float qn = fmaf(ax, ax, fmaf(ay, ay, az * az));
    float d2 = fmaxf(0.0f, qn + m);              // relu commutes with min
    atomicMin(&pmin[gq], __float_as_uint(d2));
}

// ---------------- phase 2: sum 65536 per-point d2 -> scalar ----------------
__global__ __launch_bounds__(256) void sum_kernel(
    const unsigned int* __restrict__ pmin, float* __restrict__ out)
{
    int i = blockIdx.x * 256 + threadIdx.x;   // 0..16383, 4 values each
    float4 v = ((const float4*)pmin)[i];      // bits are valid non-neg floats
    float s = v.x + v.y + v.z + v.w;
    #pragma unroll
    for (int off = 32; off > 0; off >>= 1) s += __shfl_xor(s, off);
    if ((threadIdx.x & 63) == 0) atomicAdd(out, s * (1.0f / 32768.0f));
}

// ---------------- fallback (ws too small): round-1 kernel ----------------
__global__ __launch_bounds__(1024) void chamfer_raw_kernel(
    const float* __restrict__ xraw, const float* __restrict__ yraw,
    float* __restrict__ out)
{
    __shared__ float4 red4[16][64];
    const int tid  = threadIdx.x;
    const int wave = tid >> 6;
    const int lane = tid & 63;
    const int blk  = blockIdx.x;
    const bool xdir = (blk < 128);
    const int b    = (blk & 127) >> 5;
    const int qofs = (blk & 31) << 8;
    const float* qraw = xdir ? xraw : yraw;
    const float* oraw = xdir ? yraw : xraw;
    float qx0[4], qx1[4], qx2[4], acc[4];
    #pragma unroll
    for (int q = 0; q < 4; ++q) {
        int gq = b * N_ + qofs + lane*4 + q;
        qx0[q] = qraw[gq*3+0]; qx1[q] = qraw[gq*3+1]; qx2[q] = qraw[gq*3+2];
        acc[q] = FLT_BIG;
    }
    const float* opp = oraw + (size_t)(b * N_ + wave * 512) * 3;
    #pragma unroll 4
    for (int k = 0; k < 512; ++k) {
        float p0 = opp[k*3+0], p1 = opp[k*3+1], p2 = opp[k*3+2];
        float w  = fmaf(p0, p0, fmaf(p1, p1, p2*p2));
        #pragma unroll
        for (int q = 0; q < 4; ++q) {
            float dot = qx0[q]*p0 + qx1[q]*p1 + qx2[q]*p2;
            acc[q] = fminf(acc[q], fmaf(-2.0f, dot, w));
        }
    }
    red4[wave][lane] = make_float4(acc[0], acc[1], acc[2], acc[3]);
    __syncthreads();
    if (tid < 256) {
        const float* red = (const float*)red4;
        float m = red[tid];
        #pragma unroll
        for (int w = 1; w < 16; ++w) m = fminf(m, red[w*256 + tid]);
        int gq = b * N_ + qofs + tid;
        float ax = qraw[gq*3+0], ay = qraw[gq*3+1], az = qraw[gq*3+2];
        float d2 = fmaxf(0.0f, fmaf(ax,ax,fmaf(ay,ay,az*az)) + m);
        #pragma unroll
        for (int off = 32; off > 0; off >>= 1) d2 += __shfl_xor(d2, off);
        if ((tid & 63) == 0) atomicAdd(out, d2 * (1.0f / 32768.0f));
    }
}

extern "C" void kernel_launch(void* const* d_in, const int* in_sizes, int n_in,
                              void* d_out, int out_size, void* d_ws, size_t ws_size,
                              hipStream_t stream)
{
    const float* x = (const float*)d_in[0];
    const float* y = (const float*)d_in[1];
    float* out = (float*)d_out;

    // ws layout: pmin uint[65536] = 256 KB
    const size_t need = (size_t)65536 * 4;
    if (ws_size >= need) {
        unsigned int* pmin = (unsigned int*)d_ws;
        hipMemsetAsync(pmin, 0xFF, need, stream);   // uint-min identity
        hipMemsetAsync(out, 0, 4, stream);
        chamfer_kernel<<<256, 512, 0, stream>>>(x, y, pmin);
        sum_kernel<<<64, 256, 0, stream>>>(pmin, out);
    } else {
        zero_out_kernel<<<1, 1, 0, stream>>>(out);
        chamfer_raw_kernel<<<256, 1024, 0, stream>>>(x, y, out);
    }
}

// Round 14
// 92.553 us; speedup vs baseline: 1.4774x; 1.0547x over previous
//
#include <hip/hip_runtime.h>

// ChamferLoss: x,y [4, 8192, 3] fp32 -> scalar fp32.
// out = (sum_bn min_m d2 + sum_bm min_n d2) / 32768
//
// Round 14: r9 post-mortem — symmetric systolic WORKS (42.5us, busy-time
// 24us ~= model; off-by-one fix validated, absmax 0). Remaining 18.5us
// stall = too little TLP: 1 block/CU = 2 lockstep waves/SIMD, every short
// gap (DPP hazards, dependent min3, shfl folds, fill vmcnt) stalls the
// whole SIMD. Fix: 512 blocks = 2 blocks/CU = 4 waves/SIMD; segs 4->8
// (wave sweeps 64 records = 4 ring-fills). Work unchanged, stalls now
// interleave. LDS 20KB*2=40KB/CU, VGPR 40 -> all co-resident at t=0.
// Rounds 15-18: broker timeouts (all GPUAcquisitionTimeout at acquire —
// content-independent). Cold audits across r10-r13 passed: coverage,
// colbuf bounds, protocol-free row path, occupancy math (VGPR/LDS allow
// >=4 blocks/CU; grid is the binding 2/CU), capture ordering, replay
// idempotence, same-wave colbuf lifetime. Byte-identical resubmission;
// deliberately NOT bundling the shadow-reg ILP fix — r9 implies ~60%
// per-wave stall and only a clean TLP probe discriminates interleavable
// short stalls from structural per-wave hazards.
// Predicted: chamfer ~27-31us @ VALUBusy 75-85%, occupancy ~36%,
// total ~82-86us. Falsifier A: busy% unchanged => shadow-reg pipeline
// next. Falsifier B: busy% up, dur >33us => atomics tail, widen sum.

#define N_      8192
#define RPB     4096          // pair-records per batch (y side)
#define FLT_BIG 3.0e38f

typedef float v2f __attribute__((ext_vector_type(2)));

__global__ void zero_out_kernel(float* out) { *out = 0.0f; }

// rotate one VGPR by 1 lane within each 16-lane row (DPP row_ror:1)
static __device__ __forceinline__ float rot16(float v) {
    return __uint_as_float((unsigned)__builtin_amdgcn_update_dpp(
        0, (int)__float_as_uint(v), 0x121, 0xf, 0xf, true));
}
static __device__ __forceinline__ v2f rot16v(v2f v) {
    v2f r; r.x = rot16(v.x); r.y = rot16(v.y); return r;
}

// one pair-record vs 4 query-pairs, BOTH directions.
// v = w_p - 2 q.p ; row keeps v (qn added in epilogue);
// col needs full d2 = v + qn_q (qn uncrossed: same qnv for td and ts).
// td = {v(q0,p0), v(q1,p1)}; ts = {v(q0,p1), v(q1,p0)}.
static __device__ __forceinline__ void do_record_sym(
    v2f pxs, v2f pys, v2f pzs, v2f wv,
    const v2f* qx, const v2f* qy, const v2f* qz, const v2f* qnv,
    float* acc, v2f* cacc)
{
    #pragma unroll
    for (int j = 0; j < 4; ++j) {
        v2f td, ts;
        asm("v_pk_fma_f32 %0, %1, %2, %3"
            : "=v"(td) : "v"(qz[j]), "v"(pzs), "v"(wv));
        asm("v_pk_fma_f32 %0, %1, %2, %3 op_sel:[0,1,1] op_sel_hi:[1,0,0]"
            : "=v"(ts) : "v"(qz[j]), "v"(pzs), "v"(wv));
        asm("v_pk_fma_f32 %0, %1, %2, %0"
            : "+v"(td) : "v"(qy[j]), "v"(pys));
        asm("v_pk_fma_f32 %0, %1, %2, %0 op_sel:[0,1,0] op_sel_hi:[1,0,1]"
            : "+v"(ts) : "v"(qy[j]), "v"(pys));
        asm("v_pk_fma_f32 %0, %1, %2, %0"
            : "+v"(td) : "v"(qx[j]), "v"(pxs));
        asm("v_pk_fma_f32 %0, %1, %2, %0 op_sel:[0,1,0] op_sel_hi:[1,0,1]"
            : "+v"(ts) : "v"(qx[j]), "v"(pxs));
        // row mins (x-queries), qn excluded
        asm("v_min3_f32 %0, %0, %1, %2" : "+v"(acc[2*j])   : "v"(td.x), "v"(ts.x));
        asm("v_min3_f32 %0, %0, %1, %2" : "+v"(acc[2*j+1]) : "v"(td.y), "v"(ts.y));
        // col mins (y-points), full d2: + qn (uncrossed; p0 cells are td.x,ts.y)
        v2f tdq, tsq;
        asm("v_pk_add_f32 %0, %1, %2" : "=v"(tdq) : "v"(td), "v"(qnv[j]));
        asm("v_pk_add_f32 %0, %1, %2" : "=v"(tsq) : "v"(ts), "v"(qnv[j]));
        asm("v_min3_f32 %0, %0, %1, %2" : "+v"(cacc->x) : "v"(tdq.x), "v"(tsq.y));
        asm("v_min3_f32 %0, %0, %1, %2" : "+v"(cacc->y) : "v"(tsq.x), "v"(tdq.y));
    }
}

// 512 blocks x 512 thr (8 waves), 2 blocks/CU (4 waves/SIMD). Block =
// (batch, qgroup of 512 x-queries, seg of 512 y-records). Wave sweeps 64
// records = 4 ring-fills of 16; each unique cell feeds both directions.
__global__ __launch_bounds__(512, 4) void chamfer_kernel(
    const float* __restrict__ xraw, const float* __restrict__ yraw,
    unsigned int* __restrict__ pmin)    // [2][4][8192]: x-side then y-side
{
    __shared__ float red[8 * 512];      // 16 KB (row combine)
    __shared__ float colbuf[8][128];    // 4 KB  (per-wave col mins)

    const int tid  = threadIdx.x;
    const int lane = tid & 63;
    const int wave = __builtin_amdgcn_readfirstlane(tid >> 6);
    const int blk  = blockIdx.x;        // 0..511
    const int batch = blk >> 7;
    const int qg    = (blk >> 3) & 15;
    const int seg   = blk & 7;

    // ---- load this lane's 8 x-queries (24 floats, 16B-aligned) ----
    const int qbase = batch * N_ + qg * 512;
    float f[24];
    {
        const float4* qv = (const float4*)(xraw + (size_t)qbase * 3) + lane * 6;
        #pragma unroll
        for (int k = 0; k < 6; ++k) {
            float4 t = qv[k];
            f[4*k] = t.x; f[4*k+1] = t.y; f[4*k+2] = t.z; f[4*k+3] = t.w;
        }
    }
    v2f qx[4], qy[4], qz[4], qnv[4];
    float acc[8];
    #pragma unroll
    for (int j = 0; j < 4; ++j) {
        qnv[j].x = fmaf(f[6*j+0], f[6*j+0],
                   fmaf(f[6*j+1], f[6*j+1], f[6*j+2] * f[6*j+2]));
        qnv[j].y = fmaf(f[6*j+3], f[6*j+3],
                   fmaf(f[6*j+4], f[6*j+4], f[6*j+5] * f[6*j+5]));
        qx[j] = (v2f){-2.0f * f[6*j+0], -2.0f * f[6*j+3]};
        qy[j] = (v2f){-2.0f * f[6*j+1], -2.0f * f[6*j+4]};
        qz[j] = (v2f){-2.0f * f[6*j+2], -2.0f * f[6*j+5]};
        acc[2*j] = FLT_BIG; acc[2*j+1] = FLT_BIG;
    }

    // ---- symmetric systolic sweep: 64 y-records = 4 ring-fills of 16 ----
    const int rbase = seg * 512 + wave * 64;      // wave's record base in batch
    const float2* rp = (const float2*)
        (yraw + (size_t)(batch * RPB + rbase + (lane & 15)) * 6);
    float2 A = rp[0], Bv = rp[1], Cv = rp[2];
    #pragma unroll 1
    for (int fl = 0; fl < 4; ++fl) {
        v2f pxs = (v2f){A.x,  Bv.y};
        v2f pys = (v2f){A.y,  Cv.x};
        v2f pzs = (v2f){Bv.x, Cv.y};
        v2f wv;
        wv.x = fmaf(A.x,  A.x,  fmaf(A.y,  A.y,  Bv.x * Bv.x));
        wv.y = fmaf(Bv.y, Bv.y, fmaf(Cv.x, Cv.x, Cv.y * Cv.y));
        if (fl < 3) {                    // prefetch next fill (16 recs = 48 float2)
            const float2* np = rp + (fl + 1) * 48;
            A = np[0]; Bv = np[1]; Cv = np[2];
        }
        v2f cacc = (v2f){FLT_BIG, FLT_BIG};
        #pragma unroll
        for (int s = 0; s < 16; ++s) {
            if (s) {
                pxs = rot16v(pxs); pys = rot16v(pys);
                pzs = rot16v(pzs); wv  = rot16v(wv);
                cacc = rot16v(cacc);     // col acc rides its record
            }
            do_record_sym(pxs, pys, pzs, wv, qx, qy, qz, qnv, acc, &cacc);
        }
        // 15 rotations happened; one more returns cacc to its record's
        // home lane (16 == identity, valid for either ror direction).
        cacc = rot16v(cacc);
        // fold the 4 duplicate rows, relu, stash in LDS.
        cacc.x = fminf(cacc.x, __shfl_xor(cacc.x, 16));
        cacc.x = fminf(cacc.x, __shfl_xor(cacc.x, 32));
        cacc.y = fminf(cacc.y, __shfl_xor(cacc.y, 16));
        cacc.y = fminf(cacc.y, __shfl_xor(cacc.y, 32));
        if (lane < 16) {
            colbuf[wave][fl * 32 + lane * 2]     = fmaxf(0.0f, cacc.x);
            colbuf[wave][fl * 32 + lane * 2 + 1] = fmaxf(0.0f, cacc.y);
        }
    }

    // ---- col epilogue: wave's 128 col-mins -> global atomicMin ----
    {
        unsigned int* py = pmin + 32768 + batch * N_ + 2 * rbase;
        #pragma unroll
        for (int k = 0; k < 2; ++k) {
            int idx = lane * 2 + k;              // 0..127
            float v = colbuf[wave][idx];
            atomicMin(&py[idx], __float_as_uint(v));
        }
    }

    // ---- row epilogue: block combine + relu(qn+min) -> atomicMin ----
    #pragma unroll
    for (int j = 0; j < 8; ++j) red[wave * 512 + lane * 8 + j] = acc[j];
    __syncthreads();
    float m = red[tid];                          // thread t owns query qbase+t
    #pragma unroll
    for (int w = 1; w < 8; ++w) m = fminf(m, red[w * 512 + tid]);
    int gq = qbase + tid;
    float ax = xraw[gq*3+0], ay = xraw[gq*3+1], az = xraw[gq*3+2];
    float qn = fmaf(ax, ax, fmaf(ay, ay, az * az));
    float d2 = fmaxf(0.0f, qn + m);              // relu commutes with min
    atomicMin(&pmin[gq], __float_as_uint(d2));
}

// ---------------- phase 2: sum 65536 per-point d2 -> scalar ----------------
__global__ __launch_bounds__(256) void sum_kernel(
    const unsigned int* __restrict__ pmin, float* __restrict__ out)
{
    int i = blockIdx.x * 256 + threadIdx.x;   // 0..16383, 4 values each
    float4 v = ((const float4*)pmin)[i];      // bits are valid non-neg floats
    float s = v.x + v.y + v.z + v.w;
    #pragma unroll
    for (int off = 32; off > 0; off >>= 1) s += __shfl_xor(s, off);
    if ((threadIdx.x & 63) == 0) atomicAdd(out, s * (1.0f / 32768.0f));
}

// ---------------- fallback (ws too small): round-1 kernel ----------------
__global__ __launch_bounds__(1024) void chamfer_raw_kernel(
    const float* __restrict__ xraw, const float* __restrict__ yraw,
    float* __restrict__ out)
{
    __shared__ float4 red4[16][64];
    const int tid  = threadIdx.x;
    const int wave = tid >> 6;
    const int lane = tid & 63;
    const int blk  = blockIdx.x;
    const bool xdir = (blk < 128);
    const int b    = (blk & 127) >> 5;
    const int qofs = (blk & 31) << 8;
    const float* qraw = xdir ? xraw : yraw;
    const float* oraw = xdir ? yraw : xraw;
    float qx0[4], qx1[4], qx2[4], acc[4];
    #pragma unroll
    for (int q = 0; q < 4; ++q) {
        int gq = b * N_ + qofs + lane*4 + q;
        qx0[q] = qraw[gq*3+0]; qx1[q] = qraw[gq*3+1]; qx2[q] = qraw[gq*3+2];
        acc[q] = FLT_BIG;
    }
    const float* opp = oraw + (size_t)(b * N_ + wave * 512) * 3;
    #pragma unroll 4
    for (int k = 0; k < 512; ++k) {
        float p0 = opp[k*3+0], p1 = opp[k*3+1], p2 = opp[k*3+2];
        float w  = fmaf(p0, p0, fmaf(p1, p1, p2*p2));
        #pragma unroll
        for (int q = 0; q < 4; ++q) {
            float dot = qx0[q]*p0 + qx1[q]*p1 + qx2[q]*p2;
            acc[q] = fminf(acc[q], fmaf(-2.0f, dot, w));
        }
    }
    red4[wave][lane] = make_float4(acc[0], acc[1], acc[2], acc[3]);
    __syncthreads();
    if (tid < 256) {
        const float* red = (const float*)red4;
        float m = red[tid];
        #pragma unroll
        for (int w = 1; w < 16; ++w) m = fminf(m, red[w*256 + tid]);
        int gq = b * N_ + qofs + tid;
        float ax = qraw[gq*3+0], ay = qraw[gq*3+1], az = qraw[gq*3+2];
        float d2 = fmaxf(0.0f, fmaf(ax,ax,fmaf(ay,ay,az*az)) + m);
        #pragma unroll
        for (int off = 32; off > 0; off >>= 1) d2 += __shfl_xor(d2, off);
        if ((tid & 63) == 0) atomicAdd(out, d2 * (1.0f / 32768.0f));
    }
}

extern "C" void kernel_launch(void* const* d_in, const int* in_sizes, int n_in,
                              void* d_out, int out_size, void* d_ws, size_t ws_size,
                              hipStream_t stream)
{
    const float* x = (const float*)d_in[0];
    const float* y = (const float*)d_in[1];
    float* out = (float*)d_out;

    // ws layout: pmin uint[65536] = 256 KB
    const size_t need = (size_t)65536 * 4;
    if (ws_size >= need) {
        unsigned int* pmin = (unsigned int*)d_ws;
        hipMemsetAsync(pmin, 0xFF, need, stream);   // uint-min identity
        hipMemsetAsync(out, 0, 4, stream);
        chamfer_kernel<<<512, 512, 0, stream>>>(x, y, pmin);
        sum_kernel<<<64, 256, 0, stream>>>(pmin, out);
    } else {
        zero_out_kernel<<<1, 1, 0, stream>>>(out);
        chamfer_raw_kernel<<<256, 1024, 0, stream>>>(x, y, out);
    }
}